// Round 5
// baseline (639.912 us; speedup 1.0000x reference)
//
#include <hip/hip_runtime.h>
#include <hip/hip_bf16.h>
#include <math.h>

#define N_    8
#define M_    49152
#define FIN_  64
#define K_    6
#define OUT_  64
#define E_    393216
#define ROW_  512   // FIN_*N_ elements per node row

typedef __attribute__((ext_vector_type(8))) short bf16x8;
typedef __attribute__((ext_vector_type(4))) float f32x4;

static __device__ __forceinline__ unsigned short f2bf(float f) {
    unsigned u = __float_as_uint(f);
    u += 0x7fff + ((u >> 16) & 1);   // RNE
    return (unsigned short)(u >> 16);
}
static __device__ __forceinline__ float bfl(unsigned u) { return __uint_as_float(u << 16); }
static __device__ __forceinline__ float bfh(unsigned u) { return __uint_as_float(u & 0xffff0000u); }

// ---------------- CSR build ----------------

__global__ void count_kernel(const int* __restrict__ rows, int* __restrict__ cnt) {
    int e = blockIdx.x * blockDim.x + threadIdx.x;
    if (e < E_) atomicAdd(&cnt[rows[e]], 1);
}

// Single-block scan over M_=49152 counts. Phase1: 48 register-resident chunk
// loads + wave scans. Phase2: scan of 768 wave-sums. Phase3: write out.
__global__ __launch_bounds__(1024) void scan_kernel(int* __restrict__ cntfill, int* __restrict__ rowptr) {
    __shared__ int lws[768];
    __shared__ int lw2[12];
    int t = threadIdx.x;
    int lane = t & 63, wid = t >> 6;
    int v[48], d[48];
    #pragma unroll
    for (int ch = 0; ch < 48; ++ch) v[ch] = cntfill[ch * 1024 + t];
    #pragma unroll
    for (int ch = 0; ch < 48; ++ch) {
        int s = v[ch];
        #pragma unroll
        for (int off = 1; off < 64; off <<= 1) {
            int y = __shfl_up(s, off, 64);
            if (lane >= off) s += y;
        }
        d[ch] = s - v[ch];                       // wave-exclusive
        if (lane == 63) lws[ch * 16 + wid] = s;  // wave total
    }
    __syncthreads();
    int orig = 0, s2 = 0;
    if (t < 768) {
        orig = lws[t];
        s2 = orig;
        #pragma unroll
        for (int off = 1; off < 64; off <<= 1) {
            int y = __shfl_up(s2, off, 64);
            if (lane >= off) s2 += y;
        }
        if (lane == 63) lw2[t >> 6] = s2;
    }
    __syncthreads();
    if (t == 0) {
        int run = 0;
        #pragma unroll
        for (int i = 0; i < 12; ++i) { int c = lw2[i]; lw2[i] = run; run += c; }
    }
    __syncthreads();
    if (t < 768) lws[t] = lw2[t >> 6] + s2 - orig;   // global exclusive wave offset
    __syncthreads();
    #pragma unroll
    for (int ch = 0; ch < 48; ++ch) {
        int excl = lws[ch * 16 + wid] + d[ch];
        rowptr[ch * 1024 + t]  = excl;
        cntfill[ch * 1024 + t] = excl;
    }
    if (t == 0) rowptr[M_] = E_;
}

__global__ void fill_kernel(const int* __restrict__ rows, const int* __restrict__ cols,
                            const float* __restrict__ vals, int* __restrict__ fillpos,
                            int* __restrict__ ecol, float* __restrict__ evalv,
                            int* __restrict__ eidx) {
    int e = blockIdx.x * blockDim.x + threadIdx.x;
    if (e < E_) {
        int r = rows[e];
        int p = atomicAdd(&fillpos[r], 1);
        ecol[p]  = cols[e];
        evalv[p] = vals[e];
        eidx[p]  = e;
    }
}

__global__ void sort_kernel(const int* __restrict__ rowptr, int* __restrict__ ecol,
                            float* __restrict__ evalv, int* __restrict__ eidx) {
    int m = blockIdx.x * blockDim.x + threadIdx.x;
    if (m >= M_) return;
    int s = rowptr[m], e = rowptr[m + 1];
    for (int i = s + 1; i < e; ++i) {
        int ki = eidx[i]; int kc = ecol[i]; float kv = evalv[i];
        int j = i - 1;
        while (j >= s && eidx[j] > ki) {
            eidx[j + 1] = eidx[j]; ecol[j + 1] = ecol[j]; evalv[j + 1] = evalv[j];
            --j;
        }
        eidx[j + 1] = ki; ecol[j + 1] = kc; evalv[j + 1] = kv;
    }
}

// ---------------- bf16 path ----------------

// Fused: T0[m][n*64+f] = bf16(x[n][m][f]); threads with idx<E_ also count rows.
__global__ void permute_count_kernel(const float* __restrict__ x, unsigned short* __restrict__ T0,
                                     const int* __restrict__ rows, int* __restrict__ cnt) {
    int idx = blockIdx.x * blockDim.x + threadIdx.x;   // M_*N_*16
    int f4 = idx & 15, n = (idx >> 4) & 7, m = idx >> 7;
    float4 v = ((const float4*)x)[(size_t)(n * M_ + m) * 16 + f4];
    ushort4 o;
    o.x = f2bf(v.x); o.y = f2bf(v.y); o.z = f2bf(v.z); o.w = f2bf(v.w);
    *(ushort4*)(T0 + (size_t)m * ROW_ + n * 64 + f4 * 4) = o;
    if (idx < E_) atomicAdd(&cnt[rows[idx]], 1);
}

// Fused fill + wprep. Wfrag[kk][tile][lane][i] = bf16(W[f*K+kcheb][tile*16+lane%16]),
//   kcheb = kk>>1, f = (kk&1)*32 + (lane>>4)*8 + i   (B-fragment order for 16x16x32)
__global__ void fill_wprep_kernel(const int* __restrict__ rows, const int* __restrict__ cols,
                                  const float* __restrict__ vals, int* __restrict__ fillpos,
                                  int* __restrict__ ecol, float* __restrict__ evalv,
                                  int* __restrict__ eidx,
                                  const float* __restrict__ W, unsigned short* __restrict__ Wfrag) {
    int e = blockIdx.x * blockDim.x + threadIdx.x;
    if (e < E_) {
        int r = rows[e];
        int p = atomicAdd(&fillpos[r], 1);
        ecol[p]  = cols[e];
        evalv[p] = vals[e];
        eidx[p]  = e;
    }
    if (e < 24576) {
        int i = e & 7, l = (e >> 3) & 63, tile = (e >> 9) & 3, kk = e >> 11;
        int kcheb = kk >> 1;
        int f = (kk & 1) * 32 + (l >> 4) * 8 + i;
        int o = tile * 16 + (l & 15);
        Wfrag[e] = f2bf(W[(f * K_ + kcheb) * OUT_ + o]);
    }
}

static __device__ __forceinline__ void fma_u4(float* acc, float v, uint4 u) {
    acc[0] += v * bfl(u.x); acc[1] += v * bfh(u.x);
    acc[2] += v * bfl(u.y); acc[3] += v * bfh(u.y);
    acc[4] += v * bfl(u.z); acc[5] += v * bfh(u.z);
    acc[6] += v * bfl(u.w); acc[7] += v * bfh(u.w);
}

// nxt[m] = alpha*(L@cur)[m] + beta*prev[m]; wave w: row blockIdx*4+w, lane l: 16B chunk.
// Edge metadata fetched lane-parallel then broadcast via shfl -> gathers issue
// back-to-back instead of waiting on per-edge ecol loads.
__global__ __launch_bounds__(256) void spmm_bf16_kernel(
        const unsigned short* __restrict__ cur, const unsigned short* __restrict__ prev,
        unsigned short* __restrict__ nxt,
        const int* __restrict__ rowptr, const int* __restrict__ ecol,
        const float* __restrict__ evalv, float alpha, float beta) {
    int t = threadIdx.x;
    int w = t >> 6, l = t & 63;
    int m = blockIdx.x * 4 + w;
    int s = rowptr[m], e = rowptr[m + 1];
    int cnt = e - s;
    int myc = 0; float myv = 0.f;
    if (l < cnt) { myc = ecol[s + l]; myv = evalv[s + l]; }
    uint4 p;
    if (beta != 0.f) p = *(const uint4*)(prev + (size_t)m * ROW_ + l * 8);

    float acc[8] = {0.f, 0.f, 0.f, 0.f, 0.f, 0.f, 0.f, 0.f};
    int lim = cnt < 64 ? cnt : 64;
    int i = 0;
    for (; i + 3 < lim; i += 4) {
        int c0 = __shfl(myc, i),     c1 = __shfl(myc, i + 1);
        int c2 = __shfl(myc, i + 2), c3 = __shfl(myc, i + 3);
        float v0 = __shfl(myv, i),     v1 = __shfl(myv, i + 1);
        float v2 = __shfl(myv, i + 2), v3 = __shfl(myv, i + 3);
        uint4 u0 = *(const uint4*)(cur + (size_t)c0 * ROW_ + l * 8);
        uint4 u1 = *(const uint4*)(cur + (size_t)c1 * ROW_ + l * 8);
        uint4 u2 = *(const uint4*)(cur + (size_t)c2 * ROW_ + l * 8);
        uint4 u3 = *(const uint4*)(cur + (size_t)c3 * ROW_ + l * 8);
        fma_u4(acc, v0, u0); fma_u4(acc, v1, u1);
        fma_u4(acc, v2, u2); fma_u4(acc, v3, u3);
    }
    for (; i < lim; ++i) {
        int c0 = __shfl(myc, i);
        float v0 = __shfl(myv, i);
        uint4 u0 = *(const uint4*)(cur + (size_t)c0 * ROW_ + l * 8);
        fma_u4(acc, v0, u0);
    }
    for (int j = 64; j < cnt; ++j) {   // rare (Poisson(8) tail past 64)
        int c0 = ecol[s + j];
        float v0 = evalv[s + j];
        uint4 u0 = *(const uint4*)(cur + (size_t)c0 * ROW_ + l * 8);
        fma_u4(acc, v0, u0);
    }
    #pragma unroll
    for (int j = 0; j < 8; ++j) acc[j] *= alpha;
    if (beta != 0.f) {
        acc[0] += beta * bfl(p.x); acc[1] += beta * bfh(p.x);
        acc[2] += beta * bfl(p.y); acc[3] += beta * bfh(p.y);
        acc[4] += beta * bfl(p.z); acc[5] += beta * bfh(p.z);
        acc[6] += beta * bfl(p.w); acc[7] += beta * bfh(p.w);
    }
    uint4 o;
    o.x = (unsigned)f2bf(acc[0]) | ((unsigned)f2bf(acc[1]) << 16);
    o.y = (unsigned)f2bf(acc[2]) | ((unsigned)f2bf(acc[3]) << 16);
    o.z = (unsigned)f2bf(acc[4]) | ((unsigned)f2bf(acc[5]) << 16);
    o.w = (unsigned)f2bf(acc[6]) | ((unsigned)f2bf(acc[7]) << 16);
    *(uint4*)(nxt + (size_t)m * ROW_ + l * 8) = o;
}

static __device__ __forceinline__ void epilogue_tile(
        f32x4 acc, int tile, int rbase, int col, float b,
        float* __restrict__ outn) {
    int c = tile * 16 + col;
    #pragma unroll
    for (int v = 0; v < 4; ++v) {
        float r = acc[v] + b;
        r = r > 0.f ? r : (__expf(r) - 1.f);
        outn[(size_t)(rbase + v) * OUT_ + c] = r;
    }
}

// out[n][m][o] = elu( sum_{k,f} T_k[m][n*64+f] * W[f*K+k][o] + bias[o] )
// grid M/64 blocks of 256. Block: 64 rows x all 8 n; W staged in LDS once.
// Wave w: rows blockIdx*64 + w*16 .. +15, loops over all 8 n.
__global__ __launch_bounds__(256) void combine_kernel(
        const unsigned short* __restrict__ Tbase,   // 6 buffers, stride M_*ROW_
        const unsigned short* __restrict__ Wfrag,
        const float* __restrict__ bias, float* __restrict__ out) {
    __shared__ unsigned short wlds[24576];          // 48 KB
    int t = threadIdx.x;
    {
        const uint4* src = (const uint4*)Wfrag;
        uint4* dst = (uint4*)wlds;
        #pragma unroll
        for (int i = 0; i < 12; ++i)
            dst[t + 256 * i] = src[t + 256 * i];
    }
    __syncthreads();

    int w = t >> 6, l = t & 63;
    int m0 = blockIdx.x * 64 + w * 16;
    int arow = m0 + (l & 15);
    const size_t MROW = (size_t)M_ * ROW_;
    size_t abase0 = (size_t)arow * ROW_ + (l >> 4) * 8;
    int rbase = m0 + (l >> 4) * 4;
    int col = l & 15;
    float b0 = bias[col], b1 = bias[16 + col], b2 = bias[32 + col], b3 = bias[48 + col];

    #pragma unroll
    for (int n = 0; n < 8; ++n) {
        size_t abase = abase0 + n * 64;
        bf16x8 a[12];
        #pragma unroll
        for (int kk = 0; kk < 12; ++kk)
            a[kk] = *(const bf16x8*)(Tbase + (size_t)(kk >> 1) * MROW + abase + (kk & 1) * 32);

        f32x4 acc0 = {0.f, 0.f, 0.f, 0.f};
        f32x4 acc1 = {0.f, 0.f, 0.f, 0.f};
        f32x4 acc2 = {0.f, 0.f, 0.f, 0.f};
        f32x4 acc3 = {0.f, 0.f, 0.f, 0.f};
        #pragma unroll
        for (int kk = 0; kk < 12; ++kk) {
            const unsigned short* wp = wlds + ((size_t)(kk * 4) * 64 + l) * 8;
            bf16x8 q0 = *(const bf16x8*)(wp);
            bf16x8 q1 = *(const bf16x8*)(wp + 512);
            bf16x8 q2 = *(const bf16x8*)(wp + 1024);
            bf16x8 q3 = *(const bf16x8*)(wp + 1536);
            acc0 = __builtin_amdgcn_mfma_f32_16x16x32_bf16(a[kk], q0, acc0, 0, 0, 0);
            acc1 = __builtin_amdgcn_mfma_f32_16x16x32_bf16(a[kk], q1, acc1, 0, 0, 0);
            acc2 = __builtin_amdgcn_mfma_f32_16x16x32_bf16(a[kk], q2, acc2, 0, 0, 0);
            acc3 = __builtin_amdgcn_mfma_f32_16x16x32_bf16(a[kk], q3, acc3, 0, 0, 0);
        }

        float* outn = out + (size_t)n * ((size_t)M_ * OUT_);
        epilogue_tile(acc0, 0, rbase, col, b0, outn);
        epilogue_tile(acc1, 1, rbase, col, b1, outn);
        epilogue_tile(acc2, 2, rbase, col, b2, outn);
        epilogue_tile(acc3, 3, rbase, col, b3, outn);
    }
}

// ---------------- Fallback f32 fused path ----------------

__global__ void permute_kernel(const float* __restrict__ x, float* __restrict__ A) {
    int idx = blockIdx.x * blockDim.x + threadIdx.x;
    int f4 = idx & 15;
    int n  = (idx >> 4) & 7;
    int m  = idx >> 7;
    float4 v = ((const float4*)x)[(size_t)(n * M_ + m) * 16 + f4];
    ((float4*)A)[idx] = v;
}

__global__ __launch_bounds__(512) void step_kernel(
        const float* __restrict__ cur, float* __restrict__ nxt,
        const float* __restrict__ weight, const float* __restrict__ bias,
        const int* __restrict__ rowptr, const int* __restrict__ ecol,
        const float* __restrict__ evalv, float* __restrict__ out,
        int k, float alpha, float beta, int flags) {
    __shared__ float lds_x[ROW_];
    int m = blockIdx.x;
    int t = threadIdx.x;
    lds_x[t] = cur[(size_t)m * ROW_ + t];
    if (flags & 4) {
        float acc = 0.f;
        int s = rowptr[m], e = rowptr[m + 1];
        for (int i = s; i < e; ++i)
            acc += evalv[i] * cur[(size_t)ecol[i] * ROW_ + t];
        float prevv = (beta != 0.f) ? nxt[(size_t)m * ROW_ + t] : 0.f;
        nxt[(size_t)m * ROW_ + t] = alpha * acc + beta * prevv;
    }
    __syncthreads();
    int n = t >> 6, o = t & 63;
    const float4* lx4 = (const float4*)(lds_x + n * FIN_);
    float acc = 0.f;
    #pragma unroll
    for (int f4 = 0; f4 < 16; ++f4) {
        float4 xq = lx4[f4];
        int fb = f4 * 4;
        acc += xq.x * weight[((fb + 0) * K_ + k) * OUT_ + o];
        acc += xq.y * weight[((fb + 1) * K_ + k) * OUT_ + o];
        acc += xq.z * weight[((fb + 2) * K_ + k) * OUT_ + o];
        acc += xq.w * weight[((fb + 3) * K_ + k) * OUT_ + o];
    }
    size_t oidx = (size_t)n * (M_ * OUT_) + (size_t)m * OUT_ + o;
    float res = (flags & 1) ? acc : (out[oidx] + acc);
    if (flags & 2) {
        res += bias[o];
        res = (res > 0.f) ? res : (expf(res) - 1.f);
    }
    out[oidx] = res;
}

// ---------------- launch ----------------

extern "C" void kernel_launch(void* const* d_in, const int* in_sizes, int n_in,
                              void* d_out, int out_size, void* d_ws, size_t ws_size,
                              hipStream_t stream) {
    (void)in_sizes; (void)n_in; (void)out_size;
    const float* x      = (const float*)d_in[0];
    const int*   rows   = (const int*)d_in[1];
    const int*   cols   = (const int*)d_in[2];
    const float* vals   = (const float*)d_in[3];
    const float* weight = (const float*)d_in[4];
    const float* bias   = (const float*)d_in[5];
    float* out = (float*)d_out;

    char* ws = (char*)d_ws;
    size_t off = 0;
    auto alloc = [&](size_t bytes) -> void* {
        void* p = ws + off;
        off += (bytes + 255) & ~(size_t)255;
        return p;
    };

    const size_t tbytes = (size_t)M_ * ROW_ * 2;          // 50.3 MB per bf16 T buffer
    const size_t need_new = 6 * (tbytes + 256) + (M_ + 1) * 4 + M_ * 4
                          + 3 * ((size_t)E_ * 4 + 256) + 24576 * 2 + 4096;

    if (ws_size >= need_new) {
        unsigned short* T[6];
        for (int i = 0; i < 6; ++i) T[i] = (unsigned short*)alloc(tbytes);
        int*   rowptr  = (int*)alloc((size_t)(M_ + 1) * 4);
        int*   fillpos = (int*)alloc((size_t)M_ * 4);
        int*   ecol    = (int*)alloc((size_t)E_ * 4);
        float* evalv   = (float*)alloc((size_t)E_ * 4);
        int*   eidx    = (int*)alloc((size_t)E_ * 4);
        unsigned short* Wfrag = (unsigned short*)alloc(24576 * 2);

        hipMemsetAsync(fillpos, 0, (size_t)M_ * 4, stream);
        permute_count_kernel<<<(M_ * N_ * 16) / 256, 256, 0, stream>>>(x, T[0], rows, fillpos);
        scan_kernel<<<1, 1024, 0, stream>>>(fillpos, rowptr);
        fill_wprep_kernel<<<E_ / 256, 256, 0, stream>>>(rows, cols, vals, fillpos,
                                                        ecol, evalv, eidx, weight, Wfrag);
        sort_kernel<<<M_ / 256, 256, 0, stream>>>(rowptr, ecol, evalv, eidx);

        // T1 = L T0 ; Tk = 2 L T_{k-1} - T_{k-2}
        spmm_bf16_kernel<<<M_ / 4, 256, 0, stream>>>(T[0], T[0], T[1], rowptr, ecol, evalv, 1.f, 0.f);
        spmm_bf16_kernel<<<M_ / 4, 256, 0, stream>>>(T[1], T[0], T[2], rowptr, ecol, evalv, 2.f, -1.f);
        spmm_bf16_kernel<<<M_ / 4, 256, 0, stream>>>(T[2], T[1], T[3], rowptr, ecol, evalv, 2.f, -1.f);
        spmm_bf16_kernel<<<M_ / 4, 256, 0, stream>>>(T[3], T[2], T[4], rowptr, ecol, evalv, 2.f, -1.f);
        spmm_bf16_kernel<<<M_ / 4, 256, 0, stream>>>(T[4], T[3], T[5], rowptr, ecol, evalv, 2.f, -1.f);

        combine_kernel<<<M_ / 64, 256, 0, stream>>>(T[0], Wfrag, bias, out);
    } else {
        float* A       = (float*)alloc((size_t)M_ * ROW_ * 4);
        float* B       = (float*)alloc((size_t)M_ * ROW_ * 4);
        int*   rowptr  = (int*)alloc((size_t)(M_ + 1) * 4);
        int*   fillpos = (int*)alloc((size_t)M_ * 4);
        int*   ecol    = (int*)alloc((size_t)E_ * 4);
        float* evalv   = (float*)alloc((size_t)E_ * 4);
        int*   eidx    = (int*)alloc((size_t)E_ * 4);

        permute_kernel<<<(M_ * N_ * 16) / 256, 256, 0, stream>>>(x, A);
        hipMemsetAsync(fillpos, 0, (size_t)M_ * 4, stream);
        count_kernel<<<E_ / 256, 256, 0, stream>>>(rows, fillpos);
        scan_kernel<<<1, 1024, 0, stream>>>(fillpos, rowptr);
        fill_kernel<<<E_ / 256, 256, 0, stream>>>(rows, cols, vals, fillpos, ecol, evalv, eidx);
        sort_kernel<<<M_ / 256, 256, 0, stream>>>(rowptr, ecol, evalv, eidx);

        step_kernel<<<M_, 512, 0, stream>>>(A, B, weight, bias, rowptr, ecol, evalv, out, 0, 1.f, 0.f, 1 | 4);
        step_kernel<<<M_, 512, 0, stream>>>(B, A, weight, bias, rowptr, ecol, evalv, out, 1, 2.f, -1.f, 4);
        step_kernel<<<M_, 512, 0, stream>>>(A, B, weight, bias, rowptr, ecol, evalv, out, 2, 2.f, -1.f, 4);
        step_kernel<<<M_, 512, 0, stream>>>(B, A, weight, bias, rowptr, ecol, evalv, out, 3, 2.f, -1.f, 4);
        step_kernel<<<M_, 512, 0, stream>>>(A, B, weight, bias, rowptr, ecol, evalv, out, 4, 2.f, -1.f, 4);
        step_kernel<<<M_, 512, 0, stream>>>(B, B, weight, bias, rowptr, ecol, evalv, out, 5, 0.f, 0.f, 2);
    }
}

// Round 6
// 562.031 us; speedup vs baseline: 1.1386x; 1.1386x over previous
//
#include <hip/hip_runtime.h>
#include <hip/hip_bf16.h>
#include <math.h>

#define N_    8
#define M_    49152
#define FIN_  64
#define K_    6
#define OUT_  64
#define E_    393216
#define ROW_  512   // FIN_*N_ elements per node row

typedef __attribute__((ext_vector_type(8))) short bf16x8;
typedef __attribute__((ext_vector_type(4))) float f32x4;

static __device__ __forceinline__ unsigned short f2bf(float f) {
    unsigned u = __float_as_uint(f);
    u += 0x7fff + ((u >> 16) & 1);   // RNE
    return (unsigned short)(u >> 16);
}
static __device__ __forceinline__ float bfl(unsigned u) { return __uint_as_float(u << 16); }
static __device__ __forceinline__ float bfh(unsigned u) { return __uint_as_float(u & 0xffff0000u); }

// ---------------- CSR build ----------------

__global__ void count_kernel(const int* __restrict__ rows, int* __restrict__ cnt) {
    int e = blockIdx.x * blockDim.x + threadIdx.x;
    if (e < E_) atomicAdd(&cnt[rows[e]], 1);
}

// Multi-block scan. A: per-1024-chunk local exclusive scan (48 blocks).
__global__ __launch_bounds__(1024) void scanA_kernel(const int* __restrict__ cnt,
                                                     int* __restrict__ lscan,
                                                     int* __restrict__ bsum) {
    __shared__ int wsum[16];
    int b = blockIdx.x, t = threadIdx.x, lane = t & 63, wid = t >> 6;
    int v = cnt[b * 1024 + t];
    int s = v;
    #pragma unroll
    for (int off = 1; off < 64; off <<= 1) {
        int y = __shfl_up(s, off, 64);
        if (lane >= off) s += y;
    }
    if (lane == 63) wsum[wid] = s;
    __syncthreads();
    if (t == 0) {
        int run = 0;
        #pragma unroll
        for (int i = 0; i < 16; ++i) { int c = wsum[i]; wsum[i] = run; run += c; }
        bsum[b] = run;
    }
    __syncthreads();
    lscan[b * 1024 + t] = wsum[wid] + s - v;
}

// B: exclusive scan of the 48 block sums (one wave).
__global__ void scanB_kernel(const int* __restrict__ bsum, int* __restrict__ boffs,
                             int* __restrict__ rowptr) {
    int t = threadIdx.x;   // 64
    int v = (t < 48) ? bsum[t] : 0;
    int s = v;
    #pragma unroll
    for (int off = 1; off < 64; off <<= 1) {
        int y = __shfl_up(s, off, 64);
        if (t >= off) s += y;
    }
    if (t < 48) boffs[t] = s - v;
    if (t == 0) rowptr[M_] = E_;
}

// C: add block offset; write rowptr + fill cursors.
__global__ __launch_bounds__(1024) void scanC_kernel(int* __restrict__ rowptr,
                                                     const int* __restrict__ boffs,
                                                     int* __restrict__ cntfill) {
    int b = blockIdx.x, t = threadIdx.x;
    int val = rowptr[b * 1024 + t] + boffs[b];
    rowptr[b * 1024 + t]  = val;
    cntfill[b * 1024 + t] = val;
}

__global__ void fill_kernel(const int* __restrict__ rows, const int* __restrict__ cols,
                            const float* __restrict__ vals, int* __restrict__ fillpos,
                            int* __restrict__ ecol, float* __restrict__ evalv,
                            int* __restrict__ eidx) {
    int e = blockIdx.x * blockDim.x + threadIdx.x;
    if (e < E_) {
        int r = rows[e];
        int p = atomicAdd(&fillpos[r], 1);
        ecol[p]  = cols[e];
        evalv[p] = vals[e];
        eidx[p]  = e;
    }
}

__global__ void sort_kernel(const int* __restrict__ rowptr, int* __restrict__ ecol,
                            float* __restrict__ evalv, int* __restrict__ eidx) {
    int m = blockIdx.x * blockDim.x + threadIdx.x;
    if (m >= M_) return;
    int s = rowptr[m], e = rowptr[m + 1];
    for (int i = s + 1; i < e; ++i) {
        int ki = eidx[i]; int kc = ecol[i]; float kv = evalv[i];
        int j = i - 1;
        while (j >= s && eidx[j] > ki) {
            eidx[j + 1] = eidx[j]; ecol[j + 1] = ecol[j]; evalv[j + 1] = evalv[j];
            --j;
        }
        eidx[j + 1] = ki; ecol[j + 1] = kc; evalv[j + 1] = kv;
    }
}

// ---------------- bf16 path ----------------

// Fused: T0[m][n*64+f] = bf16(x[n][m][f]); threads with idx<E_ also count rows.
__global__ void permute_count_kernel(const float* __restrict__ x, unsigned short* __restrict__ T0,
                                     const int* __restrict__ rows, int* __restrict__ cnt) {
    int idx = blockIdx.x * blockDim.x + threadIdx.x;   // M_*N_*16
    int f4 = idx & 15, n = (idx >> 4) & 7, m = idx >> 7;
    float4 v = ((const float4*)x)[(size_t)(n * M_ + m) * 16 + f4];
    ushort4 o;
    o.x = f2bf(v.x); o.y = f2bf(v.y); o.z = f2bf(v.z); o.w = f2bf(v.w);
    *(ushort4*)(T0 + (size_t)m * ROW_ + n * 64 + f4 * 4) = o;
    if (idx < E_) atomicAdd(&cnt[rows[idx]], 1);
}

// Fused fill + wprep. Wfrag[kk][tile][lane][i] = bf16(W[f*K+kcheb][tile*16+lane%16]),
//   kcheb = kk>>1, f = (kk&1)*32 + (lane>>4)*8 + i   (B-fragment order for 16x16x32)
__global__ void fill_wprep_kernel(const int* __restrict__ rows, const int* __restrict__ cols,
                                  const float* __restrict__ vals, int* __restrict__ fillpos,
                                  int* __restrict__ ecol, float* __restrict__ evalv,
                                  int* __restrict__ eidx,
                                  const float* __restrict__ W, unsigned short* __restrict__ Wfrag) {
    int e = blockIdx.x * blockDim.x + threadIdx.x;
    if (e < E_) {
        int r = rows[e];
        int p = atomicAdd(&fillpos[r], 1);
        ecol[p]  = cols[e];
        evalv[p] = vals[e];
        eidx[p]  = e;
    }
    if (e < 24576) {
        int i = e & 7, l = (e >> 3) & 63, tile = (e >> 9) & 3, kk = e >> 11;
        int kcheb = kk >> 1;
        int f = (kk & 1) * 32 + (l >> 4) * 8 + i;
        int o = tile * 16 + (l & 15);
        Wfrag[e] = f2bf(W[(f * K_ + kcheb) * OUT_ + o]);
    }
}

static __device__ __forceinline__ void fma_u4(float* acc, float v, uint4 u) {
    acc[0] += v * bfl(u.x); acc[1] += v * bfh(u.x);
    acc[2] += v * bfl(u.y); acc[3] += v * bfh(u.y);
    acc[4] += v * bfl(u.z); acc[5] += v * bfh(u.z);
    acc[6] += v * bfl(u.w); acc[7] += v * bfh(u.w);
}

// nxt[m] = alpha*(L@cur)[m] + beta*prev[m]; wave w: row blockIdx*4+w, lane l: 16B chunk.
// Edge metadata fetched lane-parallel then broadcast via shfl.
__global__ __launch_bounds__(256) void spmm_bf16_kernel(
        const unsigned short* __restrict__ cur, const unsigned short* __restrict__ prev,
        unsigned short* __restrict__ nxt,
        const int* __restrict__ rowptr, const int* __restrict__ ecol,
        const float* __restrict__ evalv, float alpha, float beta) {
    int t = threadIdx.x;
    int w = t >> 6, l = t & 63;
    int m = blockIdx.x * 4 + w;
    int s = rowptr[m], e = rowptr[m + 1];
    int cnt = e - s;
    int myc = 0; float myv = 0.f;
    if (l < cnt) { myc = ecol[s + l]; myv = evalv[s + l]; }
    uint4 p;
    if (beta != 0.f) p = *(const uint4*)(prev + (size_t)m * ROW_ + l * 8);

    float acc[8] = {0.f, 0.f, 0.f, 0.f, 0.f, 0.f, 0.f, 0.f};
    int lim = cnt < 64 ? cnt : 64;
    int i = 0;
    for (; i + 3 < lim; i += 4) {
        int c0 = __shfl(myc, i),     c1 = __shfl(myc, i + 1);
        int c2 = __shfl(myc, i + 2), c3 = __shfl(myc, i + 3);
        float v0 = __shfl(myv, i),     v1 = __shfl(myv, i + 1);
        float v2 = __shfl(myv, i + 2), v3 = __shfl(myv, i + 3);
        uint4 u0 = *(const uint4*)(cur + (size_t)c0 * ROW_ + l * 8);
        uint4 u1 = *(const uint4*)(cur + (size_t)c1 * ROW_ + l * 8);
        uint4 u2 = *(const uint4*)(cur + (size_t)c2 * ROW_ + l * 8);
        uint4 u3 = *(const uint4*)(cur + (size_t)c3 * ROW_ + l * 8);
        fma_u4(acc, v0, u0); fma_u4(acc, v1, u1);
        fma_u4(acc, v2, u2); fma_u4(acc, v3, u3);
    }
    for (; i < lim; ++i) {
        int c0 = __shfl(myc, i);
        float v0 = __shfl(myv, i);
        uint4 u0 = *(const uint4*)(cur + (size_t)c0 * ROW_ + l * 8);
        fma_u4(acc, v0, u0);
    }
    for (int j = 64; j < cnt; ++j) {   // rare tail past 64 edges/row
        int c0 = ecol[s + j];
        float v0 = evalv[s + j];
        uint4 u0 = *(const uint4*)(cur + (size_t)c0 * ROW_ + l * 8);
        fma_u4(acc, v0, u0);
    }
    #pragma unroll
    for (int j = 0; j < 8; ++j) acc[j] *= alpha;
    if (beta != 0.f) {
        acc[0] += beta * bfl(p.x); acc[1] += beta * bfh(p.x);
        acc[2] += beta * bfl(p.y); acc[3] += beta * bfh(p.y);
        acc[4] += beta * bfl(p.z); acc[5] += beta * bfh(p.z);
        acc[6] += beta * bfl(p.w); acc[7] += beta * bfh(p.w);
    }
    uint4 o;
    o.x = (unsigned)f2bf(acc[0]) | ((unsigned)f2bf(acc[1]) << 16);
    o.y = (unsigned)f2bf(acc[2]) | ((unsigned)f2bf(acc[3]) << 16);
    o.z = (unsigned)f2bf(acc[4]) | ((unsigned)f2bf(acc[5]) << 16);
    o.w = (unsigned)f2bf(acc[6]) | ((unsigned)f2bf(acc[7]) << 16);
    *(uint4*)(nxt + (size_t)m * ROW_ + l * 8) = o;
}

static __device__ __forceinline__ void epilogue_tile(
        f32x4 acc, int tile, int rbase, int col, float b,
        float* __restrict__ outn) {
    int c = tile * 16 + col;
    #pragma unroll
    for (int v = 0; v < 4; ++v) {
        float r = acc[v] + b;
        r = r > 0.f ? r : (__expf(r) - 1.f);
        outn[(size_t)(rbase + v) * OUT_ + c] = r;
    }
}

// out[n][m][o] = elu( sum_{k,f} T_k[m][n*64+f] * W[f*K+k][o] + bias[o] )
// grid M/128 blocks of 512 (8 waves x 16 rows); W staged once in 48KB LDS.
// 3 blocks/CU (LDS-limited) -> 24 waves/CU.
__global__ __launch_bounds__(512) void combine_kernel(
        const unsigned short* __restrict__ Tbase,   // 6 buffers, stride M_*ROW_
        const unsigned short* __restrict__ Wfrag,
        const float* __restrict__ bias, float* __restrict__ out) {
    __shared__ unsigned short wlds[24576];          // 48 KB
    int t = threadIdx.x;
    {
        const uint4* src = (const uint4*)Wfrag;
        uint4* dst = (uint4*)wlds;
        #pragma unroll
        for (int i = 0; i < 6; ++i)
            dst[t + 512 * i] = src[t + 512 * i];
    }
    __syncthreads();

    int w = t >> 6, l = t & 63;
    int m0 = blockIdx.x * 128 + w * 16;
    int arow = m0 + (l & 15);
    const size_t MROW = (size_t)M_ * ROW_;
    size_t abase0 = (size_t)arow * ROW_ + (l >> 4) * 8;
    int rbase = m0 + (l >> 4) * 4;
    int col = l & 15;
    float b0 = bias[col], b1 = bias[16 + col], b2 = bias[32 + col], b3 = bias[48 + col];

    #pragma unroll
    for (int n = 0; n < 8; ++n) {
        size_t abase = abase0 + n * 64;
        bf16x8 a[12];
        #pragma unroll
        for (int kk = 0; kk < 12; ++kk)
            a[kk] = *(const bf16x8*)(Tbase + (size_t)(kk >> 1) * MROW + abase + (kk & 1) * 32);

        f32x4 acc0 = {0.f, 0.f, 0.f, 0.f};
        f32x4 acc1 = {0.f, 0.f, 0.f, 0.f};
        f32x4 acc2 = {0.f, 0.f, 0.f, 0.f};
        f32x4 acc3 = {0.f, 0.f, 0.f, 0.f};
        #pragma unroll
        for (int kk = 0; kk < 12; ++kk) {
            const unsigned short* wp = wlds + ((size_t)(kk * 4) * 64 + l) * 8;
            bf16x8 q0 = *(const bf16x8*)(wp);
            bf16x8 q1 = *(const bf16x8*)(wp + 512);
            bf16x8 q2 = *(const bf16x8*)(wp + 1024);
            bf16x8 q3 = *(const bf16x8*)(wp + 1536);
            acc0 = __builtin_amdgcn_mfma_f32_16x16x32_bf16(a[kk], q0, acc0, 0, 0, 0);
            acc1 = __builtin_amdgcn_mfma_f32_16x16x32_bf16(a[kk], q1, acc1, 0, 0, 0);
            acc2 = __builtin_amdgcn_mfma_f32_16x16x32_bf16(a[kk], q2, acc2, 0, 0, 0);
            acc3 = __builtin_amdgcn_mfma_f32_16x16x32_bf16(a[kk], q3, acc3, 0, 0, 0);
        }

        float* outn = out + (size_t)n * ((size_t)M_ * OUT_);
        epilogue_tile(acc0, 0, rbase, col, b0, outn);
        epilogue_tile(acc1, 1, rbase, col, b1, outn);
        epilogue_tile(acc2, 2, rbase, col, b2, outn);
        epilogue_tile(acc3, 3, rbase, col, b3, outn);
    }
}

// ---------------- Fallback f32 fused path ----------------

__global__ void permute_kernel(const float* __restrict__ x, float* __restrict__ A) {
    int idx = blockIdx.x * blockDim.x + threadIdx.x;
    int f4 = idx & 15;
    int n  = (idx >> 4) & 7;
    int m  = idx >> 7;
    float4 v = ((const float4*)x)[(size_t)(n * M_ + m) * 16 + f4];
    ((float4*)A)[idx] = v;
}

__global__ __launch_bounds__(512) void step_kernel(
        const float* __restrict__ cur, float* __restrict__ nxt,
        const float* __restrict__ weight, const float* __restrict__ bias,
        const int* __restrict__ rowptr, const int* __restrict__ ecol,
        const float* __restrict__ evalv, float* __restrict__ out,
        int k, float alpha, float beta, int flags) {
    __shared__ float lds_x[ROW_];
    int m = blockIdx.x;
    int t = threadIdx.x;
    lds_x[t] = cur[(size_t)m * ROW_ + t];
    if (flags & 4) {
        float acc = 0.f;
        int s = rowptr[m], e = rowptr[m + 1];
        for (int i = s; i < e; ++i)
            acc += evalv[i] * cur[(size_t)ecol[i] * ROW_ + t];
        float prevv = (beta != 0.f) ? nxt[(size_t)m * ROW_ + t] : 0.f;
        nxt[(size_t)m * ROW_ + t] = alpha * acc + beta * prevv;
    }
    __syncthreads();
    int n = t >> 6, o = t & 63;
    const float4* lx4 = (const float4*)(lds_x + n * FIN_);
    float acc = 0.f;
    #pragma unroll
    for (int f4 = 0; f4 < 16; ++f4) {
        float4 xq = lx4[f4];
        int fb = f4 * 4;
        acc += xq.x * weight[((fb + 0) * K_ + k) * OUT_ + o];
        acc += xq.y * weight[((fb + 1) * K_ + k) * OUT_ + o];
        acc += xq.z * weight[((fb + 2) * K_ + k) * OUT_ + o];
        acc += xq.w * weight[((fb + 3) * K_ + k) * OUT_ + o];
    }
    size_t oidx = (size_t)n * (M_ * OUT_) + (size_t)m * OUT_ + o;
    float res = (flags & 1) ? acc : (out[oidx] + acc);
    if (flags & 2) {
        res += bias[o];
        res = (res > 0.f) ? res : (expf(res) - 1.f);
    }
    out[oidx] = res;
}

// ---------------- launch ----------------

extern "C" void kernel_launch(void* const* d_in, const int* in_sizes, int n_in,
                              void* d_out, int out_size, void* d_ws, size_t ws_size,
                              hipStream_t stream) {
    (void)in_sizes; (void)n_in; (void)out_size;
    const float* x      = (const float*)d_in[0];
    const int*   rows   = (const int*)d_in[1];
    const int*   cols   = (const int*)d_in[2];
    const float* vals   = (const float*)d_in[3];
    const float* weight = (const float*)d_in[4];
    const float* bias   = (const float*)d_in[5];
    float* out = (float*)d_out;

    char* ws = (char*)d_ws;
    size_t off = 0;
    auto alloc = [&](size_t bytes) -> void* {
        void* p = ws + off;
        off += (bytes + 255) & ~(size_t)255;
        return p;
    };

    const size_t tbytes = (size_t)M_ * ROW_ * 2;          // 50.3 MB per bf16 T buffer
    const size_t need_new = 6 * (tbytes + 256) + (M_ + 1) * 4 + M_ * 4
                          + 3 * ((size_t)E_ * 4 + 256) + 24576 * 2 + 8192;

    if (ws_size >= need_new) {
        unsigned short* T[6];
        for (int i = 0; i < 6; ++i) T[i] = (unsigned short*)alloc(tbytes);
        int*   rowptr  = (int*)alloc((size_t)(M_ + 1) * 4);
        int*   fillpos = (int*)alloc((size_t)M_ * 4);
        int*   ecol    = (int*)alloc((size_t)E_ * 4);
        float* evalv   = (float*)alloc((size_t)E_ * 4);
        int*   eidx    = (int*)alloc((size_t)E_ * 4);
        unsigned short* Wfrag = (unsigned short*)alloc(24576 * 2);
        int*   bsum    = (int*)alloc(48 * 4);
        int*   boffs   = (int*)alloc(48 * 4);

        hipMemsetAsync(fillpos, 0, (size_t)M_ * 4, stream);
        permute_count_kernel<<<(M_ * N_ * 16) / 256, 256, 0, stream>>>(x, T[0], rows, fillpos);
        scanA_kernel<<<48, 1024, 0, stream>>>(fillpos, rowptr, bsum);
        scanB_kernel<<<1, 64, 0, stream>>>(bsum, boffs, rowptr);
        scanC_kernel<<<48, 1024, 0, stream>>>(rowptr, boffs, fillpos);
        fill_wprep_kernel<<<E_ / 256, 256, 0, stream>>>(rows, cols, vals, fillpos,
                                                        ecol, evalv, eidx, weight, Wfrag);
        sort_kernel<<<M_ / 256, 256, 0, stream>>>(rowptr, ecol, evalv, eidx);

        // T1 = L T0 ; Tk = 2 L T_{k-1} - T_{k-2}
        spmm_bf16_kernel<<<M_ / 4, 256, 0, stream>>>(T[0], T[0], T[1], rowptr, ecol, evalv, 1.f, 0.f);
        spmm_bf16_kernel<<<M_ / 4, 256, 0, stream>>>(T[1], T[0], T[2], rowptr, ecol, evalv, 2.f, -1.f);
        spmm_bf16_kernel<<<M_ / 4, 256, 0, stream>>>(T[2], T[1], T[3], rowptr, ecol, evalv, 2.f, -1.f);
        spmm_bf16_kernel<<<M_ / 4, 256, 0, stream>>>(T[3], T[2], T[4], rowptr, ecol, evalv, 2.f, -1.f);
        spmm_bf16_kernel<<<M_ / 4, 256, 0, stream>>>(T[4], T[3], T[5], rowptr, ecol, evalv, 2.f, -1.f);

        combine_kernel<<<M_ / 128, 512, 0, stream>>>(T[0], Wfrag, bias, out);
    } else {
        float* A       = (float*)alloc((size_t)M_ * ROW_ * 4);
        float* B       = (float*)alloc((size_t)M_ * ROW_ * 4);
        int*   rowptr  = (int*)alloc((size_t)(M_ + 1) * 4);
        int*   fillpos = (int*)alloc((size_t)M_ * 4);
        int*   ecol    = (int*)alloc((size_t)E_ * 4);
        float* evalv   = (float*)alloc((size_t)E_ * 4);
        int*   eidx    = (int*)alloc((size_t)E_ * 4);
        int*   bsum    = (int*)alloc(48 * 4);
        int*   boffs   = (int*)alloc(48 * 4);

        permute_kernel<<<(M_ * N_ * 16) / 256, 256, 0, stream>>>(x, A);
        hipMemsetAsync(fillpos, 0, (size_t)M_ * 4, stream);
        count_kernel<<<E_ / 256, 256, 0, stream>>>(rows, fillpos);
        scanA_kernel<<<48, 1024, 0, stream>>>(fillpos, rowptr, bsum);
        scanB_kernel<<<1, 64, 0, stream>>>(bsum, boffs, rowptr);
        scanC_kernel<<<48, 1024, 0, stream>>>(rowptr, boffs, fillpos);
        fill_kernel<<<E_ / 256, 256, 0, stream>>>(rows, cols, vals, fillpos, ecol, evalv, eidx);
        sort_kernel<<<M_ / 256, 256, 0, stream>>>(rowptr, ecol, evalv, eidx);

        step_kernel<<<M_, 512, 0, stream>>>(A, B, weight, bias, rowptr, ecol, evalv, out, 0, 1.f, 0.f, 1 | 4);
        step_kernel<<<M_, 512, 0, stream>>>(B, A, weight, bias, rowptr, ecol, evalv, out, 1, 2.f, -1.f, 4);
        step_kernel<<<M_, 512, 0, stream>>>(A, B, weight, bias, rowptr, ecol, evalv, out, 2, 2.f, -1.f, 4);
        step_kernel<<<M_, 512, 0, stream>>>(B, A, weight, bias, rowptr, ecol, evalv, out, 3, 2.f, -1.f, 4);
        step_kernel<<<M_, 512, 0, stream>>>(A, B, weight, bias, rowptr, ecol, evalv, out, 4, 2.f, -1.f, 4);
        step_kernel<<<M_, 512, 0, stream>>>(B, B, weight, bias, rowptr, ecol, evalv, out, 5, 0.f, 0.f, 2);
    }
}

// Round 7
// 530.880 us; speedup vs baseline: 1.2054x; 1.0587x over previous
//
#include <hip/hip_runtime.h>
#include <hip/hip_bf16.h>
#include <math.h>

#define N_    8
#define M_    49152
#define FIN_  64
#define K_    6
#define OUT_  64
#define E_    393216
#define ROW_  512   // FIN_*N_ elements per node row

typedef __attribute__((ext_vector_type(8))) short bf16x8;
typedef __attribute__((ext_vector_type(4))) float f32x4;

static __device__ __forceinline__ unsigned short f2bf(float f) {
    unsigned u = __float_as_uint(f);
    u += 0x7fff + ((u >> 16) & 1);   // RNE
    return (unsigned short)(u >> 16);
}
static __device__ __forceinline__ float bfl(unsigned u) { return __uint_as_float(u << 16); }
static __device__ __forceinline__ float bfh(unsigned u) { return __uint_as_float(u & 0xffff0000u); }

// ---------------- CSR build ----------------

__global__ void count_kernel(const int* __restrict__ rows, int* __restrict__ cnt) {
    int e = blockIdx.x * blockDim.x + threadIdx.x;
    if (e < E_) atomicAdd(&cnt[rows[e]], 1);
}

// Multi-block scan. A: per-1024-chunk local exclusive scan (48 blocks).
__global__ __launch_bounds__(1024) void scanA_kernel(const int* __restrict__ cnt,
                                                     int* __restrict__ lscan,
                                                     int* __restrict__ bsum) {
    __shared__ int wsum[16];
    int b = blockIdx.x, t = threadIdx.x, lane = t & 63, wid = t >> 6;
    int v = cnt[b * 1024 + t];
    int s = v;
    #pragma unroll
    for (int off = 1; off < 64; off <<= 1) {
        int y = __shfl_up(s, off, 64);
        if (lane >= off) s += y;
    }
    if (lane == 63) wsum[wid] = s;
    __syncthreads();
    if (t == 0) {
        int run = 0;
        #pragma unroll
        for (int i = 0; i < 16; ++i) { int c = wsum[i]; wsum[i] = run; run += c; }
        bsum[b] = run;
    }
    __syncthreads();
    lscan[b * 1024 + t] = wsum[wid] + s - v;
}

// B: exclusive scan of the 48 block sums (one wave).
__global__ void scanB_kernel(const int* __restrict__ bsum, int* __restrict__ boffs,
                             int* __restrict__ rowptr) {
    int t = threadIdx.x;   // 64
    int v = (t < 48) ? bsum[t] : 0;
    int s = v;
    #pragma unroll
    for (int off = 1; off < 64; off <<= 1) {
        int y = __shfl_up(s, off, 64);
        if (t >= off) s += y;
    }
    if (t < 48) boffs[t] = s - v;
    if (t == 0) rowptr[M_] = E_;
}

// C: add block offset; write rowptr + fill cursors.
__global__ __launch_bounds__(1024) void scanC_kernel(int* __restrict__ rowptr,
                                                     const int* __restrict__ boffs,
                                                     int* __restrict__ cntfill) {
    int b = blockIdx.x, t = threadIdx.x;
    int val = rowptr[b * 1024 + t] + boffs[b];
    rowptr[b * 1024 + t]  = val;
    cntfill[b * 1024 + t] = val;
}

__global__ void fill_kernel(const int* __restrict__ rows, const int* __restrict__ cols,
                            const float* __restrict__ vals, int* __restrict__ fillpos,
                            int* __restrict__ ecol, float* __restrict__ evalv,
                            int* __restrict__ eidx) {
    int e = blockIdx.x * blockDim.x + threadIdx.x;
    if (e < E_) {
        int r = rows[e];
        int p = atomicAdd(&fillpos[r], 1);
        ecol[p]  = cols[e];
        evalv[p] = vals[e];
        eidx[p]  = e;
    }
}

__global__ void sort_kernel(const int* __restrict__ rowptr, int* __restrict__ ecol,
                            float* __restrict__ evalv, int* __restrict__ eidx) {
    int m = blockIdx.x * blockDim.x + threadIdx.x;
    if (m >= M_) return;
    int s = rowptr[m], e = rowptr[m + 1];
    for (int i = s + 1; i < e; ++i) {
        int ki = eidx[i]; int kc = ecol[i]; float kv = evalv[i];
        int j = i - 1;
        while (j >= s && eidx[j] > ki) {
            eidx[j + 1] = eidx[j]; ecol[j + 1] = ecol[j]; evalv[j + 1] = evalv[j];
            --j;
        }
        eidx[j + 1] = ki; ecol[j + 1] = kc; evalv[j + 1] = kv;
    }
}

// ---------------- bf16 path ----------------

// Fused: T0[m][n*64+f] = bf16(x[n][m][f]); threads with idx<E_ also count rows.
__global__ void permute_count_kernel(const float* __restrict__ x, unsigned short* __restrict__ T0,
                                     const int* __restrict__ rows, int* __restrict__ cnt) {
    int idx = blockIdx.x * blockDim.x + threadIdx.x;   // M_*N_*16
    int f4 = idx & 15, n = (idx >> 4) & 7, m = idx >> 7;
    float4 v = ((const float4*)x)[(size_t)(n * M_ + m) * 16 + f4];
    ushort4 o;
    o.x = f2bf(v.x); o.y = f2bf(v.y); o.z = f2bf(v.z); o.w = f2bf(v.w);
    *(ushort4*)(T0 + (size_t)m * ROW_ + n * 64 + f4 * 4) = o;
    if (idx < E_) atomicAdd(&cnt[rows[idx]], 1);
}

// Fused fill + wprep. Wfrag[kk][tile][lane][i] = bf16(W[f*K+kcheb][tile*16+lane%16]),
//   kcheb = kk>>1, f = (kk&1)*32 + (lane>>4)*8 + i   (B-fragment order for 16x16x32)
__global__ void fill_wprep_kernel(const int* __restrict__ rows, const int* __restrict__ cols,
                                  const float* __restrict__ vals, int* __restrict__ fillpos,
                                  int* __restrict__ ecol, float* __restrict__ evalv,
                                  int* __restrict__ eidx,
                                  const float* __restrict__ W, unsigned short* __restrict__ Wfrag) {
    int e = blockIdx.x * blockDim.x + threadIdx.x;
    if (e < E_) {
        int r = rows[e];
        int p = atomicAdd(&fillpos[r], 1);
        ecol[p]  = cols[e];
        evalv[p] = vals[e];
        eidx[p]  = e;
    }
    if (e < 24576) {
        int i = e & 7, l = (e >> 3) & 63, tile = (e >> 9) & 3, kk = e >> 11;
        int kcheb = kk >> 1;
        int f = (kk & 1) * 32 + (l >> 4) * 8 + i;
        int o = tile * 16 + (l & 15);
        Wfrag[e] = f2bf(W[(f * K_ + kcheb) * OUT_ + o]);
    }
}

static __device__ __forceinline__ void fma_u4(float* acc, float v, uint4 u) {
    acc[0] += v * bfl(u.x); acc[1] += v * bfh(u.x);
    acc[2] += v * bfl(u.y); acc[3] += v * bfh(u.y);
    acc[4] += v * bfl(u.z); acc[5] += v * bfh(u.z);
    acc[6] += v * bfl(u.w); acc[7] += v * bfh(u.w);
}

// nxt[m] = alpha*(L@cur)[m] + beta*prev[m]; wave w: row blockIdx*4+w, lane l: 16B chunk.
// Edge metadata lane-parallel + shfl broadcast; gathers batched 8-deep for MLP.
__global__ __launch_bounds__(256) void spmm_bf16_kernel(
        const unsigned short* __restrict__ cur, const unsigned short* __restrict__ prev,
        unsigned short* __restrict__ nxt,
        const int* __restrict__ rowptr, const int* __restrict__ ecol,
        const float* __restrict__ evalv, float alpha, float beta) {
    int t = threadIdx.x;
    int w = t >> 6, l = t & 63;
    int m = blockIdx.x * 4 + w;
    int s = rowptr[m], e = rowptr[m + 1];
    int cnt = e - s;
    int myc = 0; float myv = 0.f;
    if (l < cnt) { myc = ecol[s + l]; myv = evalv[s + l]; }
    uint4 p;
    if (beta != 0.f) p = *(const uint4*)(prev + (size_t)m * ROW_ + l * 8);

    float acc[8] = {0.f, 0.f, 0.f, 0.f, 0.f, 0.f, 0.f, 0.f};
    int lim = cnt < 64 ? cnt : 64;
    int i = 0;
    for (; i + 8 <= lim; i += 8) {
        int c0 = __shfl(myc, i),     c1 = __shfl(myc, i + 1);
        int c2 = __shfl(myc, i + 2), c3 = __shfl(myc, i + 3);
        int c4 = __shfl(myc, i + 4), c5 = __shfl(myc, i + 5);
        int c6 = __shfl(myc, i + 6), c7 = __shfl(myc, i + 7);
        uint4 u0 = *(const uint4*)(cur + (size_t)c0 * ROW_ + l * 8);
        uint4 u1 = *(const uint4*)(cur + (size_t)c1 * ROW_ + l * 8);
        uint4 u2 = *(const uint4*)(cur + (size_t)c2 * ROW_ + l * 8);
        uint4 u3 = *(const uint4*)(cur + (size_t)c3 * ROW_ + l * 8);
        uint4 u4 = *(const uint4*)(cur + (size_t)c4 * ROW_ + l * 8);
        uint4 u5 = *(const uint4*)(cur + (size_t)c5 * ROW_ + l * 8);
        uint4 u6 = *(const uint4*)(cur + (size_t)c6 * ROW_ + l * 8);
        uint4 u7 = *(const uint4*)(cur + (size_t)c7 * ROW_ + l * 8);
        fma_u4(acc, __shfl(myv, i),     u0); fma_u4(acc, __shfl(myv, i + 1), u1);
        fma_u4(acc, __shfl(myv, i + 2), u2); fma_u4(acc, __shfl(myv, i + 3), u3);
        fma_u4(acc, __shfl(myv, i + 4), u4); fma_u4(acc, __shfl(myv, i + 5), u5);
        fma_u4(acc, __shfl(myv, i + 6), u6); fma_u4(acc, __shfl(myv, i + 7), u7);
    }
    if (i + 4 <= lim) {
        int c0 = __shfl(myc, i),     c1 = __shfl(myc, i + 1);
        int c2 = __shfl(myc, i + 2), c3 = __shfl(myc, i + 3);
        uint4 u0 = *(const uint4*)(cur + (size_t)c0 * ROW_ + l * 8);
        uint4 u1 = *(const uint4*)(cur + (size_t)c1 * ROW_ + l * 8);
        uint4 u2 = *(const uint4*)(cur + (size_t)c2 * ROW_ + l * 8);
        uint4 u3 = *(const uint4*)(cur + (size_t)c3 * ROW_ + l * 8);
        fma_u4(acc, __shfl(myv, i),     u0); fma_u4(acc, __shfl(myv, i + 1), u1);
        fma_u4(acc, __shfl(myv, i + 2), u2); fma_u4(acc, __shfl(myv, i + 3), u3);
        i += 4;
    }
    if (i + 2 <= lim) {
        int c0 = __shfl(myc, i), c1 = __shfl(myc, i + 1);
        uint4 u0 = *(const uint4*)(cur + (size_t)c0 * ROW_ + l * 8);
        uint4 u1 = *(const uint4*)(cur + (size_t)c1 * ROW_ + l * 8);
        fma_u4(acc, __shfl(myv, i), u0); fma_u4(acc, __shfl(myv, i + 1), u1);
        i += 2;
    }
    if (i < lim) {
        int c0 = __shfl(myc, i);
        uint4 u0 = *(const uint4*)(cur + (size_t)c0 * ROW_ + l * 8);
        fma_u4(acc, __shfl(myv, i), u0);
    }
    for (int j = 64; j < cnt; ++j) {   // rare tail past 64 edges/row
        int c0 = ecol[s + j];
        float v0 = evalv[s + j];
        uint4 u0 = *(const uint4*)(cur + (size_t)c0 * ROW_ + l * 8);
        fma_u4(acc, v0, u0);
    }
    #pragma unroll
    for (int j = 0; j < 8; ++j) acc[j] *= alpha;
    if (beta != 0.f) {
        acc[0] += beta * bfl(p.x); acc[1] += beta * bfh(p.x);
        acc[2] += beta * bfl(p.y); acc[3] += beta * bfh(p.y);
        acc[4] += beta * bfl(p.z); acc[5] += beta * bfh(p.z);
        acc[6] += beta * bfl(p.w); acc[7] += beta * bfh(p.w);
    }
    uint4 o;
    o.x = (unsigned)f2bf(acc[0]) | ((unsigned)f2bf(acc[1]) << 16);
    o.y = (unsigned)f2bf(acc[2]) | ((unsigned)f2bf(acc[3]) << 16);
    o.z = (unsigned)f2bf(acc[4]) | ((unsigned)f2bf(acc[5]) << 16);
    o.w = (unsigned)f2bf(acc[6]) | ((unsigned)f2bf(acc[7]) << 16);
    *(uint4*)(nxt + (size_t)m * ROW_ + l * 8) = o;
}

static __device__ __forceinline__ void epilogue_tile(
        f32x4 acc, int tile, int rbase, int col, float b,
        float* __restrict__ outn) {
    int c = tile * 16 + col;
    #pragma unroll
    for (int v = 0; v < 4; ++v) {
        float r = acc[v] + b;
        r = r > 0.f ? r : (__expf(r) - 1.f);
        outn[(size_t)(rbase + v) * OUT_ + c] = r;
    }
}

// out[n][m][o] = elu( sum_{k,f} T_k[m][n*64+f] * W[f*K+k][o] + bias[o] )
// R4 winning geometry: grid M/32 blocks of 256 (4 waves). Block: 32 rows x 8 n.
// Wave w: row-half (w&1), n-half (w>>1) -> 4 independent n-iterations.
__global__ __launch_bounds__(256) void combine_kernel(
        const unsigned short* __restrict__ Tbase,   // 6 buffers, stride M_*ROW_
        const unsigned short* __restrict__ Wfrag,
        const float* __restrict__ bias, float* __restrict__ out) {
    __shared__ unsigned short wlds[24576];          // 48 KB
    int t = threadIdx.x;
    {
        const uint4* src = (const uint4*)Wfrag;
        uint4* dst = (uint4*)wlds;
        #pragma unroll
        for (int i = 0; i < 12; ++i)
            dst[t + 256 * i] = src[t + 256 * i];
    }
    __syncthreads();

    int w = t >> 6, l = t & 63;
    int rowhalf = w & 1, nhalf = w >> 1;
    int m0 = blockIdx.x * 32 + rowhalf * 16;
    int arow = m0 + (l & 15);
    const size_t MROW = (size_t)M_ * ROW_;
    size_t abase0 = (size_t)arow * ROW_ + (l >> 4) * 8;
    int rbase = m0 + (l >> 4) * 4;
    int col = l & 15;
    float b0 = bias[col], b1 = bias[16 + col], b2 = bias[32 + col], b3 = bias[48 + col];

    #pragma unroll
    for (int ni = 0; ni < 4; ++ni) {
        int n = nhalf * 4 + ni;
        size_t abase = abase0 + n * 64;
        bf16x8 a[12];
        #pragma unroll
        for (int kk = 0; kk < 12; ++kk)
            a[kk] = *(const bf16x8*)(Tbase + (size_t)(kk >> 1) * MROW + abase + (kk & 1) * 32);

        f32x4 acc0 = {0.f, 0.f, 0.f, 0.f};
        f32x4 acc1 = {0.f, 0.f, 0.f, 0.f};
        f32x4 acc2 = {0.f, 0.f, 0.f, 0.f};
        f32x4 acc3 = {0.f, 0.f, 0.f, 0.f};
        #pragma unroll
        for (int kk = 0; kk < 12; ++kk) {
            const unsigned short* wp = wlds + ((size_t)(kk * 4) * 64 + l) * 8;
            bf16x8 q0 = *(const bf16x8*)(wp);
            bf16x8 q1 = *(const bf16x8*)(wp + 512);
            bf16x8 q2 = *(const bf16x8*)(wp + 1024);
            bf16x8 q3 = *(const bf16x8*)(wp + 1536);
            acc0 = __builtin_amdgcn_mfma_f32_16x16x32_bf16(a[kk], q0, acc0, 0, 0, 0);
            acc1 = __builtin_amdgcn_mfma_f32_16x16x32_bf16(a[kk], q1, acc1, 0, 0, 0);
            acc2 = __builtin_amdgcn_mfma_f32_16x16x32_bf16(a[kk], q2, acc2, 0, 0, 0);
            acc3 = __builtin_amdgcn_mfma_f32_16x16x32_bf16(a[kk], q3, acc3, 0, 0, 0);
        }

        float* outn = out + (size_t)n * ((size_t)M_ * OUT_);
        epilogue_tile(acc0, 0, rbase, col, b0, outn);
        epilogue_tile(acc1, 1, rbase, col, b1, outn);
        epilogue_tile(acc2, 2, rbase, col, b2, outn);
        epilogue_tile(acc3, 3, rbase, col, b3, outn);
    }
}

// ---------------- Fallback f32 fused path ----------------

__global__ void permute_kernel(const float* __restrict__ x, float* __restrict__ A) {
    int idx = blockIdx.x * blockDim.x + threadIdx.x;
    int f4 = idx & 15;
    int n  = (idx >> 4) & 7;
    int m  = idx >> 7;
    float4 v = ((const float4*)x)[(size_t)(n * M_ + m) * 16 + f4];
    ((float4*)A)[idx] = v;
}

__global__ __launch_bounds__(512) void step_kernel(
        const float* __restrict__ cur, float* __restrict__ nxt,
        const float* __restrict__ weight, const float* __restrict__ bias,
        const int* __restrict__ rowptr, const int* __restrict__ ecol,
        const float* __restrict__ evalv, float* __restrict__ out,
        int k, float alpha, float beta, int flags) {
    __shared__ float lds_x[ROW_];
    int m = blockIdx.x;
    int t = threadIdx.x;
    lds_x[t] = cur[(size_t)m * ROW_ + t];
    if (flags & 4) {
        float acc = 0.f;
        int s = rowptr[m], e = rowptr[m + 1];
        for (int i = s; i < e; ++i)
            acc += evalv[i] * cur[(size_t)ecol[i] * ROW_ + t];
        float prevv = (beta != 0.f) ? nxt[(size_t)m * ROW_ + t] : 0.f;
        nxt[(size_t)m * ROW_ + t] = alpha * acc + beta * prevv;
    }
    __syncthreads();
    int n = t >> 6, o = t & 63;
    const float4* lx4 = (const float4*)(lds_x + n * FIN_);
    float acc = 0.f;
    #pragma unroll
    for (int f4 = 0; f4 < 16; ++f4) {
        float4 xq = lx4[f4];
        int fb = f4 * 4;
        acc += xq.x * weight[((fb + 0) * K_ + k) * OUT_ + o];
        acc += xq.y * weight[((fb + 1) * K_ + k) * OUT_ + o];
        acc += xq.z * weight[((fb + 2) * K_ + k) * OUT_ + o];
        acc += xq.w * weight[((fb + 3) * K_ + k) * OUT_ + o];
    }
    size_t oidx = (size_t)n * (M_ * OUT_) + (size_t)m * OUT_ + o;
    float res = (flags & 1) ? acc : (out[oidx] + acc);
    if (flags & 2) {
        res += bias[o];
        res = (res > 0.f) ? res : (expf(res) - 1.f);
    }
    out[oidx] = res;
}

// ---------------- launch ----------------

extern "C" void kernel_launch(void* const* d_in, const int* in_sizes, int n_in,
                              void* d_out, int out_size, void* d_ws, size_t ws_size,
                              hipStream_t stream) {
    (void)in_sizes; (void)n_in; (void)out_size;
    const float* x      = (const float*)d_in[0];
    const int*   rows   = (const int*)d_in[1];
    const int*   cols   = (const int*)d_in[2];
    const float* vals   = (const float*)d_in[3];
    const float* weight = (const float*)d_in[4];
    const float* bias   = (const float*)d_in[5];
    float* out = (float*)d_out;

    char* ws = (char*)d_ws;
    size_t off = 0;
    auto alloc = [&](size_t bytes) -> void* {
        void* p = ws + off;
        off += (bytes + 255) & ~(size_t)255;
        return p;
    };

    const size_t tbytes = (size_t)M_ * ROW_ * 2;          // 50.3 MB per bf16 T buffer
    const size_t need_new = 6 * (tbytes + 256) + (M_ + 1) * 4 + M_ * 4
                          + 3 * ((size_t)E_ * 4 + 256) + 24576 * 2 + 8192;

    if (ws_size >= need_new) {
        unsigned short* T[6];
        for (int i = 0; i < 6; ++i) T[i] = (unsigned short*)alloc(tbytes);
        int*   rowptr  = (int*)alloc((size_t)(M_ + 1) * 4);
        int*   fillpos = (int*)alloc((size_t)M_ * 4);
        int*   ecol    = (int*)alloc((size_t)E_ * 4);
        float* evalv   = (float*)alloc((size_t)E_ * 4);
        int*   eidx    = (int*)alloc((size_t)E_ * 4);
        unsigned short* Wfrag = (unsigned short*)alloc(24576 * 2);
        int*   bsum    = (int*)alloc(48 * 4);
        int*   boffs   = (int*)alloc(48 * 4);

        hipMemsetAsync(fillpos, 0, (size_t)M_ * 4, stream);
        permute_count_kernel<<<(M_ * N_ * 16) / 256, 256, 0, stream>>>(x, T[0], rows, fillpos);
        scanA_kernel<<<48, 1024, 0, stream>>>(fillpos, rowptr, bsum);
        scanB_kernel<<<1, 64, 0, stream>>>(bsum, boffs, rowptr);
        scanC_kernel<<<48, 1024, 0, stream>>>(rowptr, boffs, fillpos);
        fill_wprep_kernel<<<E_ / 256, 256, 0, stream>>>(rows, cols, vals, fillpos,
                                                        ecol, evalv, eidx, weight, Wfrag);
        sort_kernel<<<M_ / 256, 256, 0, stream>>>(rowptr, ecol, evalv, eidx);

        // T1 = L T0 ; Tk = 2 L T_{k-1} - T_{k-2}
        spmm_bf16_kernel<<<M_ / 4, 256, 0, stream>>>(T[0], T[0], T[1], rowptr, ecol, evalv, 1.f, 0.f);
        spmm_bf16_kernel<<<M_ / 4, 256, 0, stream>>>(T[1], T[0], T[2], rowptr, ecol, evalv, 2.f, -1.f);
        spmm_bf16_kernel<<<M_ / 4, 256, 0, stream>>>(T[2], T[1], T[3], rowptr, ecol, evalv, 2.f, -1.f);
        spmm_bf16_kernel<<<M_ / 4, 256, 0, stream>>>(T[3], T[2], T[4], rowptr, ecol, evalv, 2.f, -1.f);
        spmm_bf16_kernel<<<M_ / 4, 256, 0, stream>>>(T[4], T[3], T[5], rowptr, ecol, evalv, 2.f, -1.f);

        combine_kernel<<<M_ / 32, 256, 0, stream>>>(T[0], Wfrag, bias, out);
    } else {
        float* A       = (float*)alloc((size_t)M_ * ROW_ * 4);
        float* B       = (float*)alloc((size_t)M_ * ROW_ * 4);
        int*   rowptr  = (int*)alloc((size_t)(M_ + 1) * 4);
        int*   fillpos = (int*)alloc((size_t)M_ * 4);
        int*   ecol    = (int*)alloc((size_t)E_ * 4);
        float* evalv   = (float*)alloc((size_t)E_ * 4);
        int*   eidx    = (int*)alloc((size_t)E_ * 4);
        int*   bsum    = (int*)alloc(48 * 4);
        int*   boffs   = (int*)alloc(48 * 4);

        permute_kernel<<<(M_ * N_ * 16) / 256, 256, 0, stream>>>(x, A);
        hipMemsetAsync(fillpos, 0, (size_t)M_ * 4, stream);
        count_kernel<<<E_ / 256, 256, 0, stream>>>(rows, fillpos);
        scanA_kernel<<<48, 1024, 0, stream>>>(fillpos, rowptr, bsum);
        scanB_kernel<<<1, 64, 0, stream>>>(bsum, boffs, rowptr);
        scanC_kernel<<<48, 1024, 0, stream>>>(rowptr, boffs, fillpos);
        fill_kernel<<<E_ / 256, 256, 0, stream>>>(rows, cols, vals, fillpos, ecol, evalv, eidx);
        sort_kernel<<<M_ / 256, 256, 0, stream>>>(rowptr, ecol, evalv, eidx);

        step_kernel<<<M_, 512, 0, stream>>>(A, B, weight, bias, rowptr, ecol, evalv, out, 0, 1.f, 0.f, 1 | 4);
        step_kernel<<<M_, 512, 0, stream>>>(B, A, weight, bias, rowptr, ecol, evalv, out, 1, 2.f, -1.f, 4);
        step_kernel<<<M_, 512, 0, stream>>>(A, B, weight, bias, rowptr, ecol, evalv, out, 2, 2.f, -1.f, 4);
        step_kernel<<<M_, 512, 0, stream>>>(B, A, weight, bias, rowptr, ecol, evalv, out, 3, 2.f, -1.f, 4);
        step_kernel<<<M_, 512, 0, stream>>>(A, B, weight, bias, rowptr, ecol, evalv, out, 4, 2.f, -1.f, 4);
        step_kernel<<<M_, 512, 0, stream>>>(B, B, weight, bias, rowptr, ecol, evalv, out, 5, 0.f, 0.f, 2);
    }
}